// Round 14
// baseline (196.850 us; speedup 1.0000x reference)
//
#include <hip/hip_runtime.h>
#include <hip/hip_bf16.h>
#include <stdint.h>

typedef __bf16 bf16;
typedef __bf16 bf16x8 __attribute__((ext_vector_type(8)));
typedef __bf16 bf16x4 __attribute__((ext_vector_type(4)));
typedef float  f32x4  __attribute__((ext_vector_type(4)));

#define MROWS 131072   // B*H*W rows

__device__ __forceinline__ f32x4 mfma16(bf16x8 a, bf16x8 b, f32x4 c) {
    return __builtin_amdgcn_mfma_f32_16x16x32_bf16(a, b, c, 0, 0, 0);
}
__device__ __forceinline__ f32x4 zero4() {
    f32x4 z; z[0]=0.f; z[1]=0.f; z[2]=0.f; z[3]=0.f; return z;
}
__device__ __forceinline__ bf16x8 zero8() {
    bf16x8 z;
#pragma unroll
    for (int i = 0; i < 8; ++i) z[i] = (bf16)0.f;
    return z;
}
// DPP row_ror within 16-lane rows: VALU-pipe rotate-reduce (sum in all lanes).
template <int CTRL>
__device__ __forceinline__ float rowror(float x) {
    return __int_as_float(
        __builtin_amdgcn_mov_dpp(__float_as_int(x), CTRL, 0xF, 0xF, false));
}
__device__ __forceinline__ float rowsum16(float s) {
    s += rowror<0x128>(s);
    s += rowror<0x124>(s);
    s += rowror<0x122>(s);
    s += rowror<0x121>(s);
    return s;
}

// ---------------- weight transpose fp32 -> bf16: Wt[col][k] (k-contiguous) ----
__global__ void kw_transpose(const float* __restrict__ Wq, const float* __restrict__ Wkv,
                             const float* __restrict__ Wp, bf16* __restrict__ Wt,
                             bf16* __restrict__ Wpt) {
    int col = blockIdx.x;
    int k = threadIdx.x;  // 192
    if (col < 192)      Wt[col * 192 + k] = (bf16)Wq[k * 192 + col];
    else if (col < 576) Wt[col * 192 + k] = (bf16)Wkv[k * 384 + (col - 192)];
    else                Wpt[(col - 576) * 192 + k] = (bf16)Wp[k * 192 + (col - 576)];
}

// ---------------- fused QKV-GEMM + windowed attention, 2 windows/block -------
// grid 4096. slab = bid&7 -> XCD; block = (img, slab, branch, pair): windows
// A/B are adjacent wb of the SAME branch -> same X slab (L2) and same W tiles
// (L1-hot for B). Window B's X is register-staged at block start (latency
// hidden under window A), dropped into LDS at B5/B6.
// Softmax: no max pass (|S| small, masked -> exp underflow 0); normalization
// deferred to O (inv kept in regs; P stored unnormalized).
// LDS ledger (per window, regions reused):
//   [0,13312):      xs (stage->xf reads) -> qs[0..6656)+kss (->B3/B8) -> ob
//   [13312,23552):  pl (per-wave private)
//   [23552,31232):  vt
__global__ __launch_bounds__(256, 4) void kfused(const float* __restrict__ X,
                                                 const bf16* __restrict__ Wt,
                                                 bf16* __restrict__ Out) {
    const int bid = blockIdx.x;
    const int slab = bid & 7;
    const int tt = bid >> 3;                 // 0..511
    const int img = tt >> 6;                 // 0..7
    const int u = tt & 63;
    const int branch = u >> 5;
    const int pr = u & 31;                   // pair index
    const int wh = branch ? 8 : 4, ww = branch ? 4 : 8;
    const int lww = branch ? 2 : 3;          // log2(ww)
    const int sh = wh >> 1, sw = ww >> 1;

    int wa2[2], wb2[2];
#pragma unroll
    for (int e = 0; e < 2; ++e) {
        int qq = 2 * pr + e;
        wa2[e] = branch ? slab * 2 + (qq >> 5) : slab * 4 + (qq >> 4);
        wb2[e] = branch ? (qq & 31) : (qq & 15);
    }

    __shared__ __align__(16) char smem[31232];
    bf16 (*xs)[200]    = (bf16(*)[200])smem;               // stage phase
    bf16 (*qs)[104]    = (bf16(*)[104])smem;               // post xf-preload
    bf16 (*ob)[104]    = (bf16(*)[104])smem;               // post B3/B8
    bf16 (*kss)[104]   = (bf16(*)[104])(smem + 6656);
    bf16 (*pl)[32][40] = (bf16(*)[32][40])(smem + 13312);  // per-wave private
    bf16 (*vt)[24][40] = (bf16(*)[24][40])(smem + 23552);
    __shared__ int pix2[2][32];
    __shared__ int rid2[2][32];

    const int tid = threadIdx.x;
    const int hd = tid >> 6;
    const int l = tid & 63, li = l & 15, lk = l >> 4;

    if (tid < 64) {
        int e = tid >> 5, tok = tid & 31;
        int ih = tok >> lww, iw = tok & (ww - 1);
        int hh = wa2[e] * wh + ih, wp = wb2[e] * ww + iw;  // rolled coords
        int hreg = (hh >= 128 - wh) + (hh >= 128 - sh);
        int wreg = (wp >= 128 - ww) + (wp >= 128 - sw);
        rid2[e][tok] = hreg * 3 + wreg;
        int srh = (hh + sh) & 127, srw = (wp + sw) & 127;
        pix2[e][tok] = img * 16384 + srh * 128 + srw;
    }

    // ---- stage window A: global fp32 -> bf16 -> xs; window B: global -> regs ----
    bf16x8 xbr[3];
#pragma unroll
    for (int i = 0; i < 3; ++i) {
        int c = tid + i * 256;                 // 768 chunks of 8 floats
        int row = c / 24, col8 = (c % 24) * 8;
        int ih = row >> lww, iw = row & (ww - 1);
        // window A -> LDS
        {
            int hh = wa2[0] * wh + ih, wp = wb2[0] * ww + iw;
            int srh = (hh + sh) & 127, srw = (wp + sw) & 127;
            const float* p = X + (size_t)(img * 16384 + srh * 128 + srw) * 192 + col8;
            f32x4 f0 = *(const f32x4*)p;
            f32x4 f1 = *(const f32x4*)(p + 4);
            bf16x8 v;
#pragma unroll
            for (int e2 = 0; e2 < 4; ++e2) { v[e2] = (bf16)f0[e2]; v[4 + e2] = (bf16)f1[e2]; }
            *(bf16x8*)&xs[row][col8] = v;
        }
        // window B -> registers (latency hides under window A's whole pipeline)
        {
            int hh = wa2[1] * wh + ih, wp = wb2[1] * ww + iw;
            int srh = (hh + sh) & 127, srw = (wp + sw) & 127;
            const float* p = X + (size_t)(img * 16384 + srh * 128 + srw) * 192 + col8;
            f32x4 f0 = *(const f32x4*)p;
            f32x4 f1 = *(const f32x4*)(p + 4);
            bf16x8 v;
#pragma unroll
            for (int e2 = 0; e2 < 4; ++e2) { v[e2] = (bf16)f0[e2]; v[4 + e2] = (bf16)f1[e2]; }
            xbr[i] = v;
        }
    }

#define LOADW(dst, nt) {                                                            \
        int seg_ = (nt) / 6, cwi_ = ((nt) % 6) * 16;                                \
        const bf16* wr = Wt + (size_t)(seg_ * 192 + branch * 96 + cwi_ + li) * 192  \
                            + lk * 8;                                               \
        _Pragma("unroll")                                                           \
        for (int ks = 0; ks < 6; ++ks) dst[ks] = *(const bf16x8*)(wr + ks * 32);    \
    }
#define MFMA_SCATTER(frag, nt) {                                                    \
        f32x4 a0 = zero4(), a1 = zero4();                                           \
        _Pragma("unroll")                                                           \
        for (int ks = 0; ks < 6; ++ks) {                                            \
            a0 = mfma16(frag[ks], xf[0][ks], a0);                                   \
            a1 = mfma16(frag[ks], xf[1][ks], a1);                                   \
        }                                                                           \
        int seg_ = (nt) / 6, cwi_ = ((nt) % 6) * 16;                                \
        if (seg_ < 2) {                                                             \
            bf16 (*dst)[104] = (seg_ == 0) ? qs : kss;                              \
            bf16x4 p0, p1;                                                          \
            _Pragma("unroll")                                                       \
            for (int r = 0; r < 4; ++r) { p0[r] = (bf16)a0[r]; p1[r] = (bf16)a1[r]; } \
            *(bf16x4*)&dst[li][cwi_ + lk * 4] = p0;                                 \
            *(bf16x4*)&dst[16 + li][cwi_ + lk * 4] = p1;                            \
        } else {                                                                    \
            _Pragma("unroll")                                                       \
            for (int r = 0; r < 4; ++r) {                                           \
                int vc = cwi_ + lk * 4 + r;                                         \
                vt[vc / 24][vc % 24][li] = (bf16)a0[r];                             \
                vt[vc / 24][vc % 24][16 + li] = (bf16)a1[r];                        \
            }                                                                       \
        }                                                                           \
    }

#pragma unroll
    for (int win = 0; win < 2; ++win) {
        if (win == 0) {
            __syncthreads();   // B1: xs(A) + pix/rid ready
        } else {
            __syncthreads();   // B5: ob(A) reads done -> xs region free
#pragma unroll
            for (int i = 0; i < 3; ++i) {
                int c = tid + i * 256;
                int row = c / 24, col8 = (c % 24) * 8;
                *(bf16x8*)&xs[row][col8] = xbr[i];
            }
            __syncthreads();   // B6: xs(B) ready
        }

        // ---- preload X fragments ----
        bf16x8 xf[2][6];
#pragma unroll
        for (int mt = 0; mt < 2; ++mt)
#pragma unroll
            for (int ks = 0; ks < 6; ++ks)
                xf[mt][ks] = *(const bf16x8*)&xs[mt * 16 + li][ks * 32 + lk * 8];

        bf16x8 cur[6], nxt[6];
        LOADW(cur, hd);        // W loads fly across the barrier (L1-hot for win 1)
        __syncthreads();       // B1.5/B6.5: xf reads done -> qs/kss may overwrite xs

        // ---- QKV: wave hd -> n-tiles {hd, hd+4, hd+8, hd+12} (+hd+16 if hd<2) ----
#pragma unroll
        for (int j = 0; j < 4; ++j) {
            int nt = hd + 4 * j;
            if (j < 3) {
                LOADW(nxt, nt + 4);
            } else if (hd < 2) {
                LOADW(nxt, nt + 4);
            }
            MFMA_SCATTER(cur, nt);
#pragma unroll
            for (int ks = 0; ks < 6; ++ks) cur[ks] = nxt[ks];
        }
        if (hd < 2) {
            MFMA_SCATTER(cur, hd + 16);
        }
        __syncthreads();   // B2/B7: qs/kss/vt ready

        // ---- QK^T ----
        bf16x8 aq[2], bk[2];
#pragma unroll
        for (int t2 = 0; t2 < 2; ++t2) {
            if (lk < 3) {
                aq[t2] = *(const bf16x8*)&qs[t2 * 16 + li][hd * 24 + lk * 8];
                bk[t2] = *(const bf16x8*)&kss[t2 * 16 + li][hd * 24 + lk * 8];
            } else {
                aq[t2] = zero8();
                bk[t2] = zero8();
            }
        }
        f32x4 s[2][2];
#pragma unroll
        for (int it = 0; it < 2; ++it)
#pragma unroll
            for (int jt = 0; jt < 2; ++jt) s[it][jt] = mfma16(aq[it], bk[jt], zero4());

        // ---- softmax: no max pass; P stored unnormalized; inv deferred to O ----
        const float scale = 0.2041241452319315f;  // 24^-0.5
        const int r0 = lk * 4;
        const int rj0 = rid2[win][li], rj1 = rid2[win][16 + li];
        float inv_[2][4];
#pragma unroll
        for (int it = 0; it < 2; ++it) {
#pragma unroll
            for (int r = 0; r < 4; ++r) {
                int i = it * 16 + r0 + r;
                int ri = rid2[win][i];
                float v0 = s[it][0][r] * scale + ((ri != rj0) ? -100.f : 0.f);
                float v1 = s[it][1][r] * scale + ((ri != rj1) ? -100.f : 0.f);
                float e0 = __expf(v0), e1 = __expf(v1);
                pl[hd][i][li] = (bf16)e0;          // store immediately (no sum dep)
                pl[hd][i][16 + li] = (bf16)e1;
                float sm = rowsum16(e0 + e1);
                inv_[it][r] = 1.f / sm;
            }
        }
        __syncthreads();   // B3/B8: qs/kss reads done -> ob may reuse region

        // ---- O = (P @ V) * inv ----
        bf16x8 ap[2], bv[2];
#pragma unroll
        for (int it = 0; it < 2; ++it)
            ap[it] = *(const bf16x8*)&pl[hd][it * 16 + li][lk * 8];
#pragma unroll
        for (int ct = 0; ct < 2; ++ct) {
            int col = ct * 16 + li;
            if (col > 23) col = 23;               // clamp: garbage cols never written
            bv[ct] = *(const bf16x8*)&vt[hd][col][lk * 8];
        }
        f32x4 o[2][2];
#pragma unroll
        for (int it = 0; it < 2; ++it)
#pragma unroll
            for (int ct = 0; ct < 2; ++ct) o[it][ct] = mfma16(ap[it], bv[ct], zero4());

#pragma unroll
        for (int it = 0; it < 2; ++it)
#pragma unroll
            for (int ct = 0; ct < 2; ++ct) {
                int col = ct * 16 + li;
                if (col < 24) {
#pragma unroll
                    for (int r = 0; r < 4; ++r)
                        ob[it * 16 + r0 + r][hd * 24 + col] =
                            (bf16)(o[it][ct][r] * inv_[it][r]);
                }
            }
        __syncthreads();   // B4/B9: ob complete
        for (int c = tid; c < 384; c += 256) {    // 32 tokens x 12 chunks of 8
            int row = c / 12, ch = c % 12;
            *(bf16x8*)(Out + (size_t)pix2[win][row] * 192 + branch * 96 + ch * 8) =
                *(const bf16x8*)&ob[row][ch * 8];
        }
    }
#undef LOADW
#undef MFMA_SCATTER
}

// ---------------- output projection: fp32 out = Ab @ Wproj + bias --------------
#define BSTR 200
__global__ __launch_bounds__(256, 4) void kproj(const bf16* __restrict__ Ab,
                                                const bf16* __restrict__ Wpt,
                                                const float* __restrict__ bias,
                                                float* __restrict__ Out) {
    __shared__ __align__(16) bf16 Bs[96][BSTR];
    const int lid = blockIdx.x;
    const int xcd = lid & 7, s = lid >> 3;       // s: 0..255
    const int mg = xcd * 128 + s / 2;            // 0..1023
    const int nb = s & 1;
    const int tid = threadIdx.x;
    const int w = tid >> 6, l = tid & 63, li = l & 15, lk = l >> 4;
    const int rb = mg * 128 + w * 32;
    const int cb = nb * 96;

    // A-loads first (12 dwordx4 in flight)
    bf16x8 a[2][6];
#pragma unroll
    for (int it = 0; it < 2; ++it)
#pragma unroll
        for (int ks = 0; ks < 6; ++ks)
            a[it][ks] = *(const bf16x8*)(Ab + (size_t)(rb + it * 16 + li) * 192 + ks * 32 + lk * 8);

#pragma unroll
    for (int i = 0; i < 9; ++i) {
        int c = i * 256 + tid;
        int r = c / 24, col = (c % 24) * 8;
        *(bf16x8*)&Bs[r][col] = *(const bf16x8*)(Wpt + (size_t)(cb + r) * 192 + col);
    }
    __syncthreads();

    f32x4 acc[2][6];
#pragma unroll
    for (int it = 0; it < 2; ++it)
#pragma unroll
        for (int nt = 0; nt < 6; ++nt) acc[it][nt] = zero4();

#pragma unroll
    for (int nt = 0; nt < 6; ++nt) {
#pragma unroll
        for (int ks = 0; ks < 6; ++ks) {
            bf16x8 b = *(const bf16x8*)&Bs[nt * 16 + li][ks * 32 + lk * 8];
            acc[0][nt] = mfma16(b, a[0][ks], acc[0][nt]);
            acc[1][nt] = mfma16(b, a[1][ks], acc[1][nt]);
        }
    }

    // D[n][m]: row = rb+it*16+li, cols = cb+nt*16+lk*4+(0..3) -> f32x4 stores
#pragma unroll
    for (int nt = 0; nt < 6; ++nt) {
        f32x4 bv4 = *(const f32x4*)(bias + cb + nt * 16 + lk * 4);
#pragma unroll
        for (int it = 0; it < 2; ++it) {
            f32x4 ov = acc[it][nt];
#pragma unroll
            for (int r = 0; r < 4; ++r) ov[r] += bv4[r];
            *(f32x4*)(Out + (size_t)(rb + it * 16 + li) * 192 + cb + nt * 16 + lk * 4) = ov;
        }
    }
}

extern "C" void kernel_launch(void* const* d_in, const int* in_sizes, int n_in,
                              void* d_out, int out_size, void* d_ws, size_t ws_size,
                              hipStream_t stream) {
    const float* x    = (const float*)d_in[0];
    const float* Wq   = (const float*)d_in[1];
    const float* Wkv  = (const float*)d_in[2];
    const float* Wp   = (const float*)d_in[3];
    const float* bias = (const float*)d_in[4];
    float* out = (float*)d_out;

    bf16* Ab  = (bf16*)d_ws;                       // 131072 x 192 bf16 = 48 MiB
    bf16* Wt  = Ab + (size_t)MROWS * 192;          // 576 x 192
    bf16* Wpt = Wt + 576 * 192;                    // 192 x 192

    hipLaunchKernelGGL(kw_transpose, dim3(768), dim3(192), 0, stream, Wq, Wkv, Wp, Wt, Wpt);
    hipLaunchKernelGGL(kfused, dim3(4096), dim3(256), 0, stream, x, Wt, Ab);
    hipLaunchKernelGGL(kproj, dim3(2048), dim3(256), 0, stream, Ab, Wpt, bias, out);
}

// Round 15
// 144.967 us; speedup vs baseline: 1.3579x; 1.3579x over previous
//
#include <hip/hip_runtime.h>
#include <hip/hip_bf16.h>
#include <stdint.h>

typedef __bf16 bf16;
typedef __bf16 bf16x8 __attribute__((ext_vector_type(8)));
typedef __bf16 bf16x4 __attribute__((ext_vector_type(4)));
typedef float  f32x4  __attribute__((ext_vector_type(4)));

#define MROWS 131072   // B*H*W rows

__device__ __forceinline__ f32x4 mfma16(bf16x8 a, bf16x8 b, f32x4 c) {
    return __builtin_amdgcn_mfma_f32_16x16x32_bf16(a, b, c, 0, 0, 0);
}
__device__ __forceinline__ f32x4 zero4() {
    f32x4 z; z[0]=0.f; z[1]=0.f; z[2]=0.f; z[3]=0.f; return z;
}
__device__ __forceinline__ bf16x8 zero8() {
    bf16x8 z;
#pragma unroll
    for (int i = 0; i < 8; ++i) z[i] = (bf16)0.f;
    return z;
}
// DPP row_ror within 16-lane rows: VALU-pipe rotate-reduce (sum in all lanes).
template <int CTRL>
__device__ __forceinline__ float rowror(float x) {
    return __int_as_float(
        __builtin_amdgcn_mov_dpp(__float_as_int(x), CTRL, 0xF, 0xF, false));
}
__device__ __forceinline__ float rowsum16(float s) {
    s += rowror<0x128>(s);
    s += rowror<0x124>(s);
    s += rowror<0x122>(s);
    s += rowror<0x121>(s);
    return s;
}

// ---------------- weight transpose fp32 -> bf16: Wt[col][k] (k-contiguous) ----
__global__ void kw_transpose(const float* __restrict__ Wq, const float* __restrict__ Wkv,
                             const float* __restrict__ Wp, bf16* __restrict__ Wt,
                             bf16* __restrict__ Wpt) {
    int col = blockIdx.x;
    int k = threadIdx.x;  // 192
    if (col < 192)      Wt[col * 192 + k] = (bf16)Wq[k * 192 + col];
    else if (col < 576) Wt[col * 192 + k] = (bf16)Wkv[k * 384 + (col - 192)];
    else                Wpt[(col - 576) * 192 + k] = (bf16)Wp[k * 192 + (col - 576)];
}

// ---------------- fused QKV-GEMM + windowed attention ----------------
// grid 8192. XCD-slab mapping: slab = bid&7 -> XCD; slab s covers image rows
// h in [16s,16s+16): both branches of a slab read the same ~2.5 MB of X from
// that XCD's L2 (r13: FETCH 99->56 MB, verified).
// 4 waves = 4 heads. 5 barriers. LDS 31.2 KB.
// Softmax (r14-validated): no max pass (masked scores bounded; exp(-100)
// underflows to 0), P stored unnormalized, 1/sum applied to O in f32.
// LDS ledger:
//   [0, 13312):      xs[32][200] (B1->B1.5 reads) -> qs[0..6656)+kss[6656..)
//                    (B1.5->B3); ob aliases qs after B3.
//   [13312, 23552):  pl (private region, no alias)
//   [23552, 31232):  vt[96][40] (B2 -> PV reads)
__global__ __launch_bounds__(256, 4) void kfused(const float* __restrict__ X,
                                                 const bf16* __restrict__ Wt,
                                                 bf16* __restrict__ Out) {
    const int bid = blockIdx.x;
    const int slab = bid & 7;
    const int t = bid >> 3;                  // 0..1023
    const int img = t >> 7;                  // 0..7
    const int idx = t & 127;                 // 0..127
    int branch, wa, wb;
    if (idx < 64) {                          // branch 0: 4x8 windows
        branch = 0; wa = slab * 4 + (idx >> 4); wb = idx & 15;
    } else {                                 // branch 1: 8x4 windows
        branch = 1; int j = idx - 64; wa = slab * 2 + (j >> 5); wb = j & 31;
    }
    const int wh = branch ? 8 : 4, ww = branch ? 4 : 8;
    const int lww = branch ? 2 : 3;          // log2(ww)
    const int sh = wh >> 1, sw = ww >> 1;

    __shared__ __align__(16) char smem[31232];
    bf16 (*xs)[200]    = (bf16(*)[200])smem;               // pre-B1.5
    bf16 (*qs)[104]    = (bf16(*)[104])smem;               // post-B1.5
    bf16 (*ob)[104]    = (bf16(*)[104])smem;               // post-B3 (aliases qs)
    bf16 (*kss)[104]   = (bf16(*)[104])(smem + 6656);
    bf16 (*pl)[32][40] = (bf16(*)[32][40])(smem + 13312);  // private
    bf16 (*vt)[40]     = (bf16(*)[40])(smem + 23552);      // flat [96][40]
    __shared__ int pix[32];
    __shared__ int rid[32];

    const int tid = threadIdx.x;
    const int hd = tid >> 6;
    const int l = tid & 63, li = l & 15, lk = l >> 4;

    if (tid < 32) {
        int ih = tid >> lww, iw = tid & (ww - 1);
        int hh = wa * wh + ih, wp = wb * ww + iw;          // rolled coords
        int hreg = (hh >= 128 - wh) + (hh >= 128 - sh);
        int wreg = (wp >= 128 - ww) + (wp >= 128 - sw);
        rid[tid] = hreg * 3 + wreg;
        int srh = (hh + sh) & 127, srw = (wp + sw) & 127;  // source pixel
        pix[tid] = img * 16384 + srh * 128 + srw;
    }

    // ---- stage X rows: 32 x 192 fp32 -> bf16; 3 x {2 loads + 1 b128 store} ----
#pragma unroll
    for (int i = 0; i < 3; ++i) {
        int c = tid + i * 256;                 // 768 chunks of 8 floats
        int row = c / 24, col8 = (c % 24) * 8;
        int ih = row >> lww, iw = row & (ww - 1);
        int hh = wa * wh + ih, wp = wb * ww + iw;
        int srh = (hh + sh) & 127, srw = (wp + sw) & 127;
        const float* p = X + (size_t)(img * 16384 + srh * 128 + srw) * 192 + col8;
        f32x4 f0 = *(const f32x4*)p;
        f32x4 f1 = *(const f32x4*)(p + 4);
        bf16x8 v;
#pragma unroll
        for (int e = 0; e < 4; ++e) { v[e] = (bf16)f0[e]; v[4 + e] = (bf16)f1[e]; }
        *(bf16x8*)&xs[row][col8] = v;
    }
    __syncthreads();   // B1: xs + pix + rid ready

    // ---- preload X fragments ----
    bf16x8 xf[2][6];
#pragma unroll
    for (int mt = 0; mt < 2; ++mt)
#pragma unroll
        for (int ks = 0; ks < 6; ++ks)
            xf[mt][ks] = *(const bf16x8*)&xs[mt * 16 + li][ks * 32 + lk * 8];

#define LOADW(dst, nt) {                                                            \
        int seg_ = (nt) / 6, cwi_ = ((nt) % 6) * 16;                                \
        const bf16* wr = Wt + (size_t)(seg_ * 192 + branch * 96 + cwi_ + li) * 192  \
                            + lk * 8;                                               \
        _Pragma("unroll")                                                           \
        for (int ks = 0; ks < 6; ++ks) dst[ks] = *(const bf16x8*)(wr + ks * 32);    \
    }
#define MFMA_SCATTER(frag, nt) {                                                    \
        f32x4 a0 = zero4(), a1 = zero4();                                           \
        _Pragma("unroll")                                                           \
        for (int ks = 0; ks < 6; ++ks) {                                            \
            a0 = mfma16(frag[ks], xf[0][ks], a0);                                   \
            a1 = mfma16(frag[ks], xf[1][ks], a1);                                   \
        }                                                                           \
        int seg_ = (nt) / 6, cwi_ = ((nt) % 6) * 16;                                \
        if (seg_ < 2) {                                                             \
            bf16 (*dst)[104] = (seg_ == 0) ? qs : kss;                              \
            bf16x4 p0, p1;                                                          \
            _Pragma("unroll")                                                       \
            for (int r = 0; r < 4; ++r) { p0[r] = (bf16)a0[r]; p1[r] = (bf16)a1[r]; } \
            *(bf16x4*)&dst[li][cwi_ + lk * 4] = p0;                                 \
            *(bf16x4*)&dst[16 + li][cwi_ + lk * 4] = p1;                            \
        } else {                                                                    \
            _Pragma("unroll")                                                       \
            for (int r = 0; r < 4; ++r) {                                           \
                int vc = cwi_ + lk * 4 + r;                                         \
                vt[vc][li] = (bf16)a0[r];                                           \
                vt[vc][16 + li] = (bf16)a1[r];                                      \
            }                                                                       \
        }                                                                           \
    }

    bf16x8 cur[6], nxt[6];
    LOADW(cur, hd);        // first W-tile loads fly across the barrier
    __syncthreads();       // B1.5: all xf reads done -> qs/kss may overwrite xs

    // ---- QKV: wave hd -> n-tiles {hd, hd+4, hd+8, hd+12} (+hd+16 if hd<2) ----
#pragma unroll
    for (int j = 0; j < 4; ++j) {
        int nt = hd + 4 * j;
        if (j < 3) {
            LOADW(nxt, nt + 4);
        } else if (hd < 2) {               // wave-uniform tail prefetch
            LOADW(nxt, nt + 4);
        }
        MFMA_SCATTER(cur, nt);
#pragma unroll
        for (int ks = 0; ks < 6; ++ks) cur[ks] = nxt[ks];
    }
    if (hd < 2) {                          // tail tile nt = hd+16
        MFMA_SCATTER(cur, hd + 16);
    }
    __syncthreads();   // B2: qs/kss/vt ready

    // ---- attention: QK^T ----
    bf16x8 aq[2], bk[2];
#pragma unroll
    for (int t2 = 0; t2 < 2; ++t2) {
        if (lk < 3) {
            aq[t2] = *(const bf16x8*)&qs[t2 * 16 + li][hd * 24 + lk * 8];
            bk[t2] = *(const bf16x8*)&kss[t2 * 16 + li][hd * 24 + lk * 8];
        } else {
            aq[t2] = zero8();
            bk[t2] = zero8();
        }
    }
    f32x4 s[2][2];
#pragma unroll
    for (int it = 0; it < 2; ++it)
#pragma unroll
        for (int jt = 0; jt < 2; ++jt) s[it][jt] = mfma16(aq[it], bk[jt], zero4());

    // ---- softmax: no max pass; P stored unnormalized; inv kept in regs ----
    const float scale = 0.2041241452319315f;  // 24^-0.5
    const int r0 = lk * 4;
    const int rj0 = rid[li], rj1 = rid[16 + li];
    float inv_[2][4];
#pragma unroll
    for (int it = 0; it < 2; ++it) {
#pragma unroll
        for (int r = 0; r < 4; ++r) {
            int i = it * 16 + r0 + r;
            int ri = rid[i];
            float v0 = s[it][0][r] * scale + ((ri != rj0) ? -100.f : 0.f);
            float v1 = s[it][1][r] * scale + ((ri != rj1) ? -100.f : 0.f);
            float e0 = __expf(v0), e1 = __expf(v1);
            pl[hd][i][li] = (bf16)e0;          // store immediately (no sum dep)
            pl[hd][i][16 + li] = (bf16)e1;
            float sm = rowsum16(e0 + e1);
            inv_[it][r] = 1.f / sm;
        }
    }
    __syncthreads();   // B3: all qs/kss reads done -> ob may reuse qs region

    // ---- O = (P @ V) * inv ----
    bf16x8 ap[2], bv[2];
#pragma unroll
    for (int it = 0; it < 2; ++it)
        ap[it] = *(const bf16x8*)&pl[hd][it * 16 + li][lk * 8];
#pragma unroll
    for (int ct = 0; ct < 2; ++ct) {
        int col = ct * 16 + li;
        if (col > 23) col = 23;               // clamp: garbage cols never written
        bv[ct] = *(const bf16x8*)&vt[hd * 24 + col][lk * 8];
    }
    f32x4 o[2][2];
#pragma unroll
    for (int it = 0; it < 2; ++it)
#pragma unroll
        for (int ct = 0; ct < 2; ++ct) o[it][ct] = mfma16(ap[it], bv[ct], zero4());

    // stage O in LDS (ob aliases qs, freed at B3), coalesced writeback
#pragma unroll
    for (int it = 0; it < 2; ++it)
#pragma unroll
        for (int ct = 0; ct < 2; ++ct) {
            int col = ct * 16 + li;
            if (col < 24) {
#pragma unroll
                for (int r = 0; r < 4; ++r)
                    ob[it * 16 + r0 + r][hd * 24 + col] =
                        (bf16)(o[it][ct][r] * inv_[it][r]);
            }
        }
    __syncthreads();   // B4: ob complete
    for (int c = tid; c < 384; c += 256) {    // 32 tokens x 12 chunks of 8
        int row = c / 12, ch = c % 12;
        *(bf16x8*)(Out + (size_t)pix[row] * 192 + branch * 96 + ch * 8) =
            *(const bf16x8*)&ob[row][ch * 8];
    }
#undef LOADW
#undef MFMA_SCATTER
}

// ---------------- output projection: fp32 out = Ab @ Wproj + bias --------------
#define BSTR 200
__global__ __launch_bounds__(256, 4) void kproj(const bf16* __restrict__ Ab,
                                                const bf16* __restrict__ Wpt,
                                                const float* __restrict__ bias,
                                                float* __restrict__ Out) {
    __shared__ __align__(16) bf16 Bs[96][BSTR];
    const int lid = blockIdx.x;
    const int xcd = lid & 7, s = lid >> 3;       // s: 0..255
    const int mg = xcd * 128 + s / 2;            // 0..1023
    const int nb = s & 1;
    const int tid = threadIdx.x;
    const int w = tid >> 6, l = tid & 63, li = l & 15, lk = l >> 4;
    const int rb = mg * 128 + w * 32;
    const int cb = nb * 96;

    // A-loads first (12 dwordx4 in flight)
    bf16x8 a[2][6];
#pragma unroll
    for (int it = 0; it < 2; ++it)
#pragma unroll
        for (int ks = 0; ks < 6; ++ks)
            a[it][ks] = *(const bf16x8*)(Ab + (size_t)(rb + it * 16 + li) * 192 + ks * 32 + lk * 8);

#pragma unroll
    for (int i = 0; i < 9; ++i) {
        int c = i * 256 + tid;
        int r = c / 24, col = (c % 24) * 8;
        *(bf16x8*)&Bs[r][col] = *(const bf16x8*)(Wpt + (size_t)(cb + r) * 192 + col);
    }
    __syncthreads();

    f32x4 acc[2][6];
#pragma unroll
    for (int it = 0; it < 2; ++it)
#pragma unroll
        for (int nt = 0; nt < 6; ++nt) acc[it][nt] = zero4();

#pragma unroll
    for (int nt = 0; nt < 6; ++nt) {
#pragma unroll
        for (int ks = 0; ks < 6; ++ks) {
            bf16x8 b = *(const bf16x8*)&Bs[nt * 16 + li][ks * 32 + lk * 8];
            acc[0][nt] = mfma16(b, a[0][ks], acc[0][nt]);
            acc[1][nt] = mfma16(b, a[1][ks], acc[1][nt]);
        }
    }

    // D[n][m]: row = rb+it*16+li, cols = cb+nt*16+lk*4+(0..3) -> f32x4 stores
#pragma unroll
    for (int nt = 0; nt < 6; ++nt) {
        f32x4 bv4 = *(const f32x4*)(bias + cb + nt * 16 + lk * 4);
#pragma unroll
        for (int it = 0; it < 2; ++it) {
            f32x4 ov = acc[it][nt];
#pragma unroll
            for (int r = 0; r < 4; ++r) ov[r] += bv4[r];
            *(f32x4*)(Out + (size_t)(rb + it * 16 + li) * 192 + cb + nt * 16 + lk * 4) = ov;
        }
    }
}

extern "C" void kernel_launch(void* const* d_in, const int* in_sizes, int n_in,
                              void* d_out, int out_size, void* d_ws, size_t ws_size,
                              hipStream_t stream) {
    const float* x    = (const float*)d_in[0];
    const float* Wq   = (const float*)d_in[1];
    const float* Wkv  = (const float*)d_in[2];
    const float* Wp   = (const float*)d_in[3];
    const float* bias = (const float*)d_in[4];
    float* out = (float*)d_out;

    bf16* Ab  = (bf16*)d_ws;                       // 131072 x 192 bf16 = 48 MiB
    bf16* Wt  = Ab + (size_t)MROWS * 192;          // 576 x 192
    bf16* Wpt = Wt + 576 * 192;                    // 192 x 192

    hipLaunchKernelGGL(kw_transpose, dim3(768), dim3(192), 0, stream, Wq, Wkv, Wp, Wt, Wpt);
    hipLaunchKernelGGL(kfused, dim3(8192), dim3(256), 0, stream, x, Wt, Ab);
    hipLaunchKernelGGL(kproj, dim3(2048), dim3(256), 0, stream, Ab, Wpt, bias, out);
}